// Round 4
// baseline (274.545 us; speedup 1.0000x reference)
//
#include <hip/hip_runtime.h>

#define HH  512
#define WW  512
#define RAD 10
#define KK  21
#define SEG 8                   // output rows per block
#define NRAW (SEG + 2 * RAD)    // 28 raw rows per block
#define LSTRIDE 540             // LDS row stride (floats): 532 used, 16B-aligned

typedef float vfloat4 __attribute__((ext_vector_type(4)));  // clang-native, OK for
                                                            // __builtin_nontemporal_store

// Fused separable Gaussian blur (21x21, sigma=3), reflect padding.
// v4b: occupancy-first. SEG=8, 256 threads (4 waves), float2 cols.
//   - LDS 17.3 KB -> 8 blocks/CU * 4 waves = 32 waves/CU (100% cap; v2 was
//     66% measured with 34.8 KB / 8-wave blocks).
//   - 6144 fine-grained blocks (24/CU): load-phase and compute-phase blocks
//     naturally interleave on each CU -> latency hidden by TLP, not by
//     fragile in-thread pipelining (v3's register ring spilled to scratch:
//     VGPR=40 + 24MB extra FETCH + 35MB extra WRITE = spill traffic).
//   - float2 raw loads: half the load instrs/waits of v2's scalar loads.
//   - Nontemporal float4 stores: output is never re-read; keep L2/L3 for
//     the halo re-reads (3.5x read amplification, L3-resident).
//   - Straight-line static indexing only -> no scratch at the 64-VGPR cap
//     of __launch_bounds__(256,8).
__global__ __launch_bounds__(256, 8) void gauss_blur_kernel(
    const float* __restrict__ x, float* __restrict__ out)
{
    // g[d] = exp(-d^2/18), w = g/sum(g); 2D kernel = outer(w,w) exactly.
    const float wt[KK] = {
        0.00051432f, 0.00147793f, 0.00380033f, 0.00874446f, 0.01800488f,
        0.03317359f, 0.05469399f, 0.08069227f, 0.10652936f, 0.12584957f,
        0.13303907f,
        0.12584957f, 0.10652936f, 0.08069227f, 0.05469399f, 0.03317359f,
        0.01800488f, 0.00874446f, 0.00380033f, 0.00147793f, 0.00051432f
    };

    __shared__ __align__(16) float vbuf[SEG * LSTRIDE];   // 17.28 KB

    // XCD-contiguous bijective remap: 6144 blocks % 8 == 0.
    const int bid = blockIdx.y * gridDim.x + blockIdx.x;
    const int cpx = (gridDim.x * gridDim.y) >> 3;          // 768
    const int lid = (bid & 7) * cpx + (bid >> 3);
    const int y0  = (lid & 63) * SEG;                      // gridDim.x == 64
    const int img = lid >> 6;

    const int t  = threadIdx.x;
    const int c0 = 2 * t;          // this thread's columns: c0, c0+1
    const int c1 = c0 + 1;

    const float* xim = x   + (size_t)img * (HH * WW);
    float*       oim = out + (size_t)img * (HH * WW);

    // ---------------- Phase 1: raw rows -> vertical blur -> LDS -------------
    float2 rows[NRAW];
    #pragma unroll
    for (int i = 0; i < NRAW; ++i) {
        int r  = y0 - RAD + i;
        int rr = r < 0 ? -r : (r > HH - 1 ? 2 * (HH - 1) - r : r);
        rows[i] = *(const float2*)(xim + rr * WW + c0);
    }

    #pragma unroll
    for (int r = 0; r < SEG; ++r) {
        float vx = 0.f, vy = 0.f;
        #pragma unroll
        for (int k = 0; k < KK; ++k) {
            vx = fmaf(wt[k], rows[r + k].x, vx);
            vy = fmaf(wt[k], rows[r + k].y, vy);
        }
        float* vb = vbuf + r * LSTRIDE;
        *(float2*)(vb + RAD + c0) = make_float2(vx, vy);
        // reflect pads in x
        if (c0 >= 1 && c0 <= RAD)           vb[RAD - c0] = vx;
        if (c1 <= RAD)                      vb[RAD - c1] = vy;
        if (c0 >= WW - 11 && c0 <= WW - 2)  vb[RAD + 2 * (WW - 1) - c0] = vx;
        if (c1 >= WW - 11 && c1 <= WW - 2)  vb[RAD + 2 * (WW - 1) - c1] = vy;
    }

    __syncthreads();   // the only barrier

    // ---------------- Phase 2: horizontal blur ----------------
    // 256 tasks, one per thread: row r = t & 7, col-group q = t >> 3 (16 cols).
    const int r = t & (SEG - 1);
    const int q = t >> 3;                                  // 0..31
    // padded window start = RAD + (q*16 - RAD) = q*16 -> 16B aligned
    const float* vr = vbuf + r * LSTRIDE + q * 16;

    float wnd[36];
    #pragma unroll
    for (int j = 0; j < 9; ++j) {                          // 9x ds_read_b128
        float4 v4 = *(const float4*)(vr + 4 * j);
        wnd[4*j]   = v4.x; wnd[4*j+1] = v4.y;
        wnd[4*j+2] = v4.z; wnd[4*j+3] = v4.w;
    }

    float acc[16];
    #pragma unroll
    for (int j = 0; j < 16; ++j) {
        float s = 0.f;
        #pragma unroll
        for (int k = 0; k < KK; ++k)
            s = fmaf(wt[k], wnd[j + k], s);
        acc[j] = s;
    }

    float* op = oim + (size_t)(y0 + r) * WW + q * 16;
    #pragma unroll
    for (int j = 0; j < 4; ++j) {
        vfloat4 o4 = { acc[4*j], acc[4*j+1], acc[4*j+2], acc[4*j+3] };
        __builtin_nontemporal_store(o4, (vfloat4*)(op + 4 * j));
    }
}

extern "C" void kernel_launch(void* const* d_in, const int* in_sizes, int n_in,
                              void* d_out, int out_size, void* d_ws, size_t ws_size,
                              hipStream_t stream) {
    const float* x = (const float*)d_in[0];
    float* out = (float*)d_out;
    const int n_img = in_sizes[0] / (HH * WW);     // 32*3 = 96
    dim3 grid(HH / SEG, n_img);                    // (64, 96) = 6144 blocks
    gauss_blur_kernel<<<grid, dim3(256), 0, stream>>>(x, out);
}

// Round 5
// 209.492 us; speedup vs baseline: 1.3105x; 1.3105x over previous
//
#include <hip/hip_runtime.h>
#include <stdint.h>

#define HH   512
#define WW   512
#define RAD  10
#define KK   21
#define SEG  16                 // output rows per tile
#define TILES 4                 // tiles per block -> 64 output rows
#define RING 52                 // raw-row ring slots (36 live + 16 prefetch)
#define LSTRIDE 540             // vbuf row stride (floats), 16B-aligned

// Fused separable Gaussian blur (21x21, sigma=3), reflect padding.
// v5: async-pipelined LDS raw-row ring.
//   - v2's limiter: convoying + shallow load MLP (VGPR=28 -> ~6 loads in
//     flight -> ~5 serialized latency batches/wave; VALUBusy capped at 35%).
//   - Fix: raw rows live in a 52-slot LDS ring filled by
//     __builtin_amdgcn_global_load_lds (zero VGPR cost, all 16 next-tile
//     rows in flight). Issue prefetch BEFORE the vertical conv: ~900cy of
//     FMA covers the latency; the mid-tile __syncthreads drains vmcnt.
//   - Vertical conv streams 36 ds_read_b32/col (64 consecutive lanes/row =
//     2-way bank alias = free) scatter-accumulating into acc[16].
//   - Loads: 36 + 3*16 = 84 rows / 64 output rows = 1.31x (v2: 2.25x).
//   - LDS 137.75 KB -> 1 block/CU; occupancy ~25% BY DESIGN (latency hidden
//     by the async pipeline, not TLP -- TLP maxed out at 35% VALU in v1-v4).
//   - Stores cached (v4b lesson: scattered stores need L2 write-combining;
//     nontemporal caused 2.6x write amplification).
__global__ __launch_bounds__(512, 2) void gauss_blur_kernel(
    const float* __restrict__ x, float* __restrict__ out)
{
    // g[d] = exp(-d^2/18), w = g/sum(g); 2D kernel = outer(w,w) exactly.
    const float wt[KK] = {
        0.00051432f, 0.00147793f, 0.00380033f, 0.00874446f, 0.01800488f,
        0.03317359f, 0.05469399f, 0.08069227f, 0.10652936f, 0.12584957f,
        0.13303907f,
        0.12584957f, 0.10652936f, 0.08069227f, 0.05469399f, 0.03317359f,
        0.01800488f, 0.00874446f, 0.00380033f, 0.00147793f, 0.00051432f
    };

    __shared__ __align__(16) float raw[RING * WW];       // 106496 B
    __shared__ __align__(16) float vbuf[SEG * LSTRIDE];  //  34560 B  -> 137.75 KB

    // XCD-contiguous bijective remap: 768 blocks % 8 == 0.
    const int bid = blockIdx.y * gridDim.x + blockIdx.x;
    const int cpx = (gridDim.x * gridDim.y) >> 3;        // 96
    const int lid = (bid & 7) * cpx + (bid >> 3);
    const int bs  = lid & 7;                             // block-strip 0..7
    const int img = lid >> 3;

    const int t    = threadIdx.x;                        // 0..511 = column
    const int wave = t >> 6;                             // 0..7
    const int lane = t & 63;

    const float* xim = x   + (size_t)img * (HH * WW);
    float*       oim = out + (size_t)img * (HH * WW);

    const int strip0 = bs * TILES;                       // first strip (of 32)

    // ---------------- prologue: async-load first 36 raw rows ----------------
    // 36 rows x 2 half-rows = 72 chunks; each wave issues 9 (wave-uniform
    // row/slot -> uniform LDS base; global addr is per-lane, 64x16B = 1KB).
    #pragma unroll
    for (int k = 0; k < 9; ++k) {
        const int chunk = wave * 9 + k;                  // 0..71, wave-uniform
        const int i     = chunk >> 1;                    // row index 0..35
        const int half  = chunk & 1;
        const int r     = strip0 * SEG - RAD + i;
        const int rr    = r < 0 ? -r : (r > HH - 1 ? 2 * (HH - 1) - r : r);
        const int slot  = (r + RAD) % RING;
        __builtin_amdgcn_global_load_lds(
            (const __attribute__((address_space(1))) void*)
                (xim + rr * WW + half * 256 + lane * 4),
            (__attribute__((address_space(3))) void*)
                (raw + slot * WW + half * 256),
            16, 0, 0);
    }
    __syncthreads();    // drains vmcnt: ring holds tile-0's 36 rows

    // ---------------- tile loop ---------------------------------------------
    for (int s = 0; s < TILES; ++s) {
        const int strip = strip0 + s;
        const int y0    = strip * SEG;

        // (1) async-prefetch next tile's 16 NEW rows (y0+26 .. y0+41) into
        //     ring slots that are dead for the current tile. 4 instrs/wave.
        if (s + 1 < TILES) {
            #pragma unroll
            for (int k = 0; k < 4; ++k) {
                const int j    = 2 * wave + (k >> 1);    // 0..15, uniform
                const int half = k & 1;
                const int r    = y0 + 26 + j;
                const int rr   = r > HH - 1 ? 2 * (HH - 1) - r : r;
                const int slot = (r + RAD) % RING;
                __builtin_amdgcn_global_load_lds(
                    (const __attribute__((address_space(1))) void*)
                        (xim + rr * WW + half * 256 + lane * 4),
                    (__attribute__((address_space(3))) void*)
                        (raw + slot * WW + half * 256),
                    16, 0, 0);
            }
        }

        // (2) vertical conv: stream 36 ring rows, scatter into acc[16].
        {
            float acc[SEG];
            #pragma unroll
            for (int r = 0; r < SEG; ++r) acc[r] = 0.f;

            const int sb = y0 % RING;    // slot of logical row (y0 - RAD)
            #pragma unroll
            for (int i = 0; i < 36; ++i) {
                int slot = sb + i; if (slot >= RING) slot -= RING;
                const float f = raw[slot * WW + t];
                const int lo = (i - 2 * RAD) < 0 ? 0 : (i - 2 * RAD);
                const int hi = i < (SEG - 1) ? i : (SEG - 1);
                #pragma unroll
                for (int r = lo; r <= hi; ++r)
                    acc[r] = fmaf(wt[i - r], f, acc[r]);
            }
            #pragma unroll
            for (int r = 0; r < SEG; ++r) {
                float* vb = vbuf + r * LSTRIDE;
                vb[RAD + t] = acc[r];
                // reflect pads in x
                if (t >= 1 && t <= RAD)               vb[RAD - t] = acc[r];
                if (t >= WW - 1 - RAD && t <= WW - 2) vb[RAD + 2 * (WW - 1) - t] = acc[r];
            }
        }

        __syncthreads();   // vbuf ready; prefetch vmcnt drained (covered by FMAs)

        // (3) horizontal conv (v2-proven): task t -> (row t&15, 16-col group t>>4)
        {
            const int r = t & (SEG - 1);
            const int q = t >> 4;                        // 0..31
            const float* vr = vbuf + r * LSTRIDE + q * 16;  // q*16: 16B-aligned

            float wnd[36];
            #pragma unroll
            for (int j = 0; j < 9; ++j) {                // 9x ds_read_b128
                float4 v4 = *(const float4*)(vr + 4 * j);
                wnd[4*j]   = v4.x; wnd[4*j+1] = v4.y;
                wnd[4*j+2] = v4.z; wnd[4*j+3] = v4.w;
            }

            float acc[16];
            #pragma unroll
            for (int j = 0; j < 16; ++j) {
                float ss = 0.f;
                #pragma unroll
                for (int k = 0; k < KK; ++k)
                    ss = fmaf(wt[k], wnd[j + k], ss);
                acc[j] = ss;
            }

            float* op = oim + (size_t)(y0 + r) * WW + q * 16;
            #pragma unroll
            for (int j = 0; j < 4; ++j)
                *(float4*)(op + 4 * j) =
                    make_float4(acc[4*j], acc[4*j+1], acc[4*j+2], acc[4*j+3]);
        }

        __syncthreads();   // vbuf reads done before next tile overwrites it
    }
}

extern "C" void kernel_launch(void* const* d_in, const int* in_sizes, int n_in,
                              void* d_out, int out_size, void* d_ws, size_t ws_size,
                              hipStream_t stream) {
    const float* x = (const float*)d_in[0];
    float* out = (float*)d_out;
    const int n_img = in_sizes[0] / (HH * WW);     // 32*3 = 96
    dim3 grid(HH / (SEG * TILES), n_img);          // (8, 96) = 768 blocks
    gauss_blur_kernel<<<grid, dim3(512), 0, stream>>>(x, out);
}

// Round 6
// 183.896 us; speedup vs baseline: 1.4929x; 1.1392x over previous
//
#include <hip/hip_runtime.h>

#define HH  512
#define WW  512
#define RAD 10
#define KK  21
#define SEG 16        // output rows per block
#define NROWS (SEG + 2 * RAD)   // 36 raw rows per block
#define LSTRIDE 540   // LDS row stride (floats): 532 used, 16B-aligned

// Fused separable Gaussian blur (21x21, sigma=3), reflect padding.
// v6 = v2 (best: 67.5us/dispatch) + ONE lever: pinned deep load burst.
//   - v2's VGPR_Count=28 proved the compiler sank the 36 loads into the
//     conv loop (~6 in flight -> ~7 serialized latency batches/wave).
//   - __builtin_amdgcn_sched_barrier(0) after the load loop pins all 36
//     loads before any FMA: 36 live dest VGPRs (~52 total < 64 cap of
//     (512,8)), one vmcnt wait instead of seven.
//   - Everything else byte-identical to v2: SEG=16, 512 threads, scalar
//     cols, LDS 34.8KB -> 4 blocks/CU, XCD-bijective remap, 1 barrier.
//   - Known-but-deferred: phase-2 ds_read_b128 pattern costs ~19 extra
//     cyc/read (SQ_LDS_BANK_CONFLICT = exactly 4177920 in v1/v2/v5).
__global__ __launch_bounds__(512, 8) void gauss_blur_kernel(
    const float* __restrict__ x, float* __restrict__ out)
{
    // g[d] = exp(-d^2/18), w = g/sum(g); 2D kernel = outer(w,w) exactly.
    const float wt[KK] = {
        0.00051432f, 0.00147793f, 0.00380033f, 0.00874446f, 0.01800488f,
        0.03317359f, 0.05469399f, 0.08069227f, 0.10652936f, 0.12584957f,
        0.13303907f,
        0.12584957f, 0.10652936f, 0.08069227f, 0.05469399f, 0.03317359f,
        0.01800488f, 0.00874446f, 0.00380033f, 0.00147793f, 0.00051432f
    };

    __shared__ __align__(16) float vbuf[SEG * LSTRIDE];   // 34.56 KB

    // XCD-contiguous bijective remap: 3072 blocks % 8 == 0.
    const int bid = blockIdx.y * gridDim.x + blockIdx.x;
    const int cpx = (gridDim.x * gridDim.y) >> 3;          // 384
    const int lid = (bid & 7) * cpx + (bid >> 3);
    const int y0  = (lid & 31) * SEG;                      // gridDim.x == 32
    const int img = lid >> 5;

    const int t = threadIdx.x;                             // 0..511 = column

    const float* xim = x   + (size_t)img * (HH * WW);
    float*       oim = out + (size_t)img * (HH * WW);

    // ---------------- Phase 1: preload all 36 raw rows ----------------------
    float rows[NROWS];
    #pragma unroll
    for (int i = 0; i < NROWS; ++i) {
        int r  = y0 - RAD + i;
        int rr = r < 0 ? -r : (r > HH - 1 ? 2 * (HH - 1) - r : r);
        rows[i] = xim[rr * WW + t];
    }
    // Pin: no instruction (esp. the conv FMAs) may be scheduled before this
    // point, so all 36 loads are issued back-to-back -> one latency wait.
    __builtin_amdgcn_sched_barrier(0);

    // ---------------- vertical blur -> LDS ----------------
    #pragma unroll
    for (int r = 0; r < SEG; ++r) {
        float v = 0.f;
        #pragma unroll
        for (int k = 0; k < KK; ++k)
            v = fmaf(wt[k], rows[r + k], v);
        float* vb = vbuf + r * LSTRIDE;
        vb[RAD + t] = v;
        // reflect pads in x
        if (t >= 1 && t <= RAD)                   vb[RAD - t] = v;
        if (t >= WW - 1 - RAD && t <= WW - 2)     vb[RAD + 2 * (WW - 1) - t] = v;
    }

    __syncthreads();   // the only barrier

    // ---------------- Phase 2: horizontal blur ----------------
    // 512 tasks, one per thread: row r = t & 15, col-group q = t >> 4 (16 cols).
    const int r = t & (SEG - 1);
    const int q = t >> 4;                                  // 0..31
    // padded window start = RAD + (q*16 - RAD) = q*16 -> 16B aligned
    const float* vr = vbuf + r * LSTRIDE + q * 16;

    float wnd[36];
    #pragma unroll
    for (int j = 0; j < 9; ++j) {                          // 9x ds_read_b128
        float4 v4 = *(const float4*)(vr + 4 * j);
        wnd[4*j]   = v4.x; wnd[4*j+1] = v4.y;
        wnd[4*j+2] = v4.z; wnd[4*j+3] = v4.w;
    }

    float acc[16];
    #pragma unroll
    for (int j = 0; j < 16; ++j) {
        float s = 0.f;
        #pragma unroll
        for (int k = 0; k < KK; ++k)
            s = fmaf(wt[k], wnd[j + k], s);
        acc[j] = s;
    }

    float* op = oim + (size_t)(y0 + r) * WW + q * 16;
    #pragma unroll
    for (int j = 0; j < 4; ++j)
        *(float4*)(op + 4 * j) =
            make_float4(acc[4*j], acc[4*j+1], acc[4*j+2], acc[4*j+3]);
}

extern "C" void kernel_launch(void* const* d_in, const int* in_sizes, int n_in,
                              void* d_out, int out_size, void* d_ws, size_t ws_size,
                              hipStream_t stream) {
    const float* x = (const float*)d_in[0];
    float* out = (float*)d_out;
    const int n_img = in_sizes[0] / (HH * WW);     // 32*3 = 96
    dim3 grid(HH / SEG, n_img);                    // (32, 96) = 3072 blocks
    gauss_blur_kernel<<<grid, dim3(512), 0, stream>>>(x, out);
}